// Round 1
// baseline (222.876 us; speedup 1.0000x reference)
//
#include <hip/hip_runtime.h>
#include <math.h>

// Problem constants
#define B_   8
#define C_   64
#define H_   128
#define W_   128
#define HW_  16384
#define K2_  9

typedef float f32x4 __attribute__((ext_vector_type(4)));
typedef short bf16x8 __attribute__((ext_vector_type(8)));
typedef unsigned short u16x4 __attribute__((ext_vector_type(4)));
typedef unsigned int u32x4 __attribute__((ext_vector_type(4)));

// Workspace layout (float offsets):
//   wrP  deform A-frags bf16    @ 8192     (36864 us)
//   wrP2 offmod A-frags bf16    @ 26624    (18432 us)
//   xt   [B][H][W][64] bf16     @ 45056    (2097152 us)
//   om   [B][y][c 0..27][px]    @ 8433664  (3670016 f)  c: 0-8 dy, 9-17 dx, 18-26 mod
#define WS_WRP  8192
#define WS_WRP2 26624
#define WS_XT   45056
#define WS_OM   8433664

static __device__ __forceinline__ unsigned short f2bf(float x) {
    unsigned int u = __float_as_uint(x);
    unsigned int r = (u + 0x7fffu + ((u >> 16) & 1u)) >> 16;   // RNE
    return (unsigned short)r;
}
static __device__ __forceinline__ float bf2f(unsigned short u) {
    return __uint_as_float(((unsigned int)u) << 16);
}
// packed f32x2 -> bf16x2 (RNE), single instruction on gfx950
static __device__ __forceinline__ unsigned int cvt_pk_bf16(float lo, float hi) {
    unsigned int r;
    asm("v_cvt_pk_bf16_f32 %0, %1, %2" : "=v"(r) : "v"(lo), "v"(hi));
    return r;
}

// ---------------------------------------------------------------------------
// Kernel 1: 1x1 fuse conv as bf16 MFMA GEMM (LDS A-frag build, direct B loads)
// + weight packing for later kernels folded into blocks 0..17.
// M=64 (o), N=64 (half row), K=128. grid = B*H*2 = 2048,
// blockIdx = (y*2+h)*8 + b. Wave wv owns px [h*64+wv*16, +16).
// A-frag convention (16x16x32): m = mt*16+(lane&15), k = kc*32+(lane>>4)*8+j.
// ---------------------------------------------------------------------------
__global__ __launch_bounds__(256) void k_fuse(const float* __restrict__ xi,
                                              const float* __restrict__ xc,
                                              const float* __restrict__ wf,
                                              const float* __restrict__ wreg,
                                              const float* __restrict__ wOff,
                                              const float* __restrict__ wMod,
                                              unsigned short* __restrict__ xtb,
                                              unsigned short* __restrict__ wrP,
                                              unsigned short* __restrict__ wrP2) {
    __shared__ unsigned short sA[1024 * 8];   // 16 KB: [f=kc*4+mt][lane][8]
    const int t = threadIdx.x;
    const int lane = t & 63;
    const int wv = t >> 6;
    const int b = blockIdx.x & 7;
    const int yh = blockIdx.x >> 3;
    const int y = yh >> 1;
    const int h = yh & 1;

    // ---- pack wrP / wrP2 (blocks 0..17 only; consumed by later kernels) ----
    if (blockIdx.x < 18) {
        const int idx = blockIdx.x * 256 + t;
        if (idx < 4608) {
            int ln = idx & 63, mt = (idx >> 6) & 3, kc = (idx >> 8) & 1, tap = idx >> 9;
            int o = mt * 16 + (ln & 15);
            int ibase = kc * 32 + (ln >> 4) * 8;
#pragma unroll
            for (int j = 0; j < 8; ++j)
                wrP[idx * 8 + j] = f2bf(wreg[(o * 64 + ibase + j) * 9 + tap]);
        }
        if (idx < 2304) {
            int ln = idx & 63, mt = (idx >> 6) & 1, kc = idx >> 7;
            int m = mt * 16 + (ln & 15);
            int gkb = kc * 32 + (ln >> 4) * 8;
#pragma unroll
            for (int j = 0; j < 8; ++j) {
                int gk = gkb + j, tap = gk >> 6, ci = gk & 63;
                float v = 0.f;
                if (m < 18)      v = wOff[(m * 64 + ci) * 9 + tap];
                else if (m < 27) v = wMod[((m - 18) * 64 + ci) * 9 + tap];
                wrP2[idx * 8 + j] = f2bf(v);
            }
        }
    }

    // ---- build fuse A-frags in LDS (each block; 32 f2bf8-chunks /thread/4) --
#pragma unroll
    for (int r = 0; r < 4; ++r) {
        const int c = t + 256 * r;      // chunk 0..1023
        const int f = c >> 6;           // f = kc*4 + mt
        const int ln = c & 63;
        const int mt = f & 3, kc = f >> 2;
        const int m = mt * 16 + (ln & 15);
        const int kb = kc * 32 + (ln >> 4) * 8;
        const float* s = wf + m * 128 + kb;
        unsigned short us[8];
#pragma unroll
        for (int j = 0; j < 8; ++j) us[j] = f2bf(s[j]);
        *(bf16x8*)&sA[c * 8] = *(const bf16x8*)us;
    }
    __syncthreads();

    const int n15 = lane & 15;
    const int q4 = lane >> 4;
    const int px = h * 64 + wv * 16 + n15;
    const size_t poff = (size_t)y * W_ + px;

    f32x4 acc[4];
#pragma unroll
    for (int mt = 0; mt < 4; ++mt) acc[mt] = (f32x4){0.f, 0.f, 0.f, 0.f};

#pragma unroll
    for (int kc = 0; kc < 4; ++kc) {
        const float* src = (kc < 2)
            ? (xi + ((size_t)(b * 64 + kc * 32 + q4 * 8)) * HW_ + poff)
            : (xc + ((size_t)(b * 64 + (kc - 2) * 32 + q4 * 8)) * HW_ + poff);
        unsigned short us[8];
#pragma unroll
        for (int j = 0; j < 8; ++j) us[j] = f2bf(src[(size_t)j * HW_]);
        const bf16x8 bf = *(const bf16x8*)us;
#pragma unroll
        for (int mt = 0; mt < 4; ++mt) {
            const bf16x8 a = *(const bf16x8*)&sA[((kc * 4 + mt) * 64 + lane) * 8];
            acc[mt] = __builtin_amdgcn_mfma_f32_16x16x32_bf16(a, bf, acc[mt], 0, 0, 0);
        }
    }

#pragma unroll
    for (int mt = 0; mt < 4; ++mt) {
        u16x4 o4;
        o4.x = f2bf(acc[mt][0]); o4.y = f2bf(acc[mt][1]);
        o4.z = f2bf(acc[mt][2]); o4.w = f2bf(acc[mt][3]);
        *(u16x4*)&xtb[((size_t)b * HW_ + poff) * 64 + mt * 16 + q4 * 4] = o4;
    }
}

// ---------------------------------------------------------------------------
// Kernel 2: 3x3 off+mod convs as im2col bf16 MFMA GEMM. om layout [c][px].
// ---------------------------------------------------------------------------
__global__ __launch_bounds__(256) void k_offmod(const unsigned short* __restrict__ xtb,
                                                const unsigned short* __restrict__ wrP2,
                                                const float* __restrict__ bOff,
                                                const float* __restrict__ bMod,
                                                float* __restrict__ om) {
    __shared__ unsigned short sB[3 * 66 * 72];   // 28512 B
    const int t = threadIdx.x;
    const int lane = t & 63;
    const int wv = t >> 6;
    const int b = blockIdx.x & 7;
    const int yh = blockIdx.x >> 3;
    const int y = yh >> 1;
    const int h = yh & 1;

    for (int idx = t; idx < 3 * 66 * 8; idx += 256) {
        const int c8 = idx & 7;
        const int pp = (idx >> 3) % 66;
        const int row = (idx >> 3) / 66;
        const int gx = h * 64 + pp - 1;
        const int gy = y + row - 1;
        bf16x8 v = {0, 0, 0, 0, 0, 0, 0, 0};
        if (gx >= 0 && gx < W_ && gy >= 0 && gy < H_)
            v = *(const bf16x8*)&xtb[(((size_t)(b * H_ + gy)) * W_ + gx) * 64 + c8 * 8];
        *(bf16x8*)&sB[(row * 66 + pp) * 72 + c8 * 8] = v;
    }
    __syncthreads();

    const int n15 = lane & 15;
    const int q4 = lane >> 4;

    f32x4 acc[2];
    acc[0] = (f32x4){0.f, 0.f, 0.f, 0.f};
    acc[1] = (f32x4){0.f, 0.f, 0.f, 0.f};

#pragma unroll
    for (int kc = 0; kc < 18; ++kc) {
        const int gkb = kc * 32 + q4 * 8;
        const int tap = gkb >> 6;
        const int ci = gkb & 63;
        const int row = tap / 3, kx = tap % 3;
        const bf16x8 bf = *(const bf16x8*)&sB[(row * 66 + (wv * 16 + n15 + kx)) * 72 + ci];
        const bf16x8 a0 = *(const bf16x8*)(wrP2 + (((size_t)(kc * 2 + 0) * 64 + lane) * 8));
        const bf16x8 a1 = *(const bf16x8*)(wrP2 + (((size_t)(kc * 2 + 1) * 64 + lane) * 8));
        acc[0] = __builtin_amdgcn_mfma_f32_16x16x32_bf16(a0, bf, acc[0], 0, 0, 0);
        acc[1] = __builtin_amdgcn_mfma_f32_16x16x32_bf16(a1, bf, acc[1], 0, 0, 0);
    }

    const int px = h * 64 + wv * 16 + n15;
    const size_t rec = ((size_t)(b * H_ + y)) * 28 * 128;
#pragma unroll
    for (int mt = 0; mt < 2; ++mt)
#pragma unroll
        for (int r = 0; r < 4; ++r) {
            const int o = mt * 16 + q4 * 4 + r;
            if (o < 18) {
                const int c = (o >> 1) + ((o & 1) ? 9 : 0);
                om[rec + c * 128 + px] = acc[mt][r] + bOff[o];
            } else if (o < 27) {
                const float z = acc[mt][r] + bMod[o - 18];
                om[rec + (18 + (o - 18)) * 128 + px] = 2.f / (1.f + __expf(-z));
            }
        }
}

// ---------------------------------------------------------------------------
// Kernel 3: deformable sampling + modulation + bf16 MFMA einsum.
// grid = B*H*2 = 2048, 4 waves x 16 px. ZERO LDS, ZERO barriers.
// B-frag layout for 16x16x32: n = lane&15 (px), k = kc*32 + (lane>>4)*8 + j
// (channel). xtb records are channel-contiguous (128 B), so each lane gathers
// its own 8-channel group for its px directly: per tap, 8 global_load_dwordx4
// (4 corners x 2 kc, 16 B each), blends the 4 corners in registers with its
// per-px bilinear*mod weights, and v_cvt_pk_bf16_f32 packs straight into the
// B-fragment. Replaces the previous readlane-broadcast + LDS-staging Phase B
// (64 x 2-byte gathers + 16 ds_write + bank-conflicted ds_read per wave-tap).
// ---------------------------------------------------------------------------
__global__ __launch_bounds__(256) void k_deform(const unsigned short* __restrict__ xtb,
                                                const float* __restrict__ om,
                                                const unsigned short* __restrict__ wrP,
                                                float* __restrict__ out) {
    const int t = threadIdx.x;
    const int lane = t & 63;
    const int wv = t >> 6;
    const int b = blockIdx.x & 7;
    const int yh = blockIdx.x >> 3;
    const int y = yh >> 1;
    const int h = yh & 1;

    const char* xbB = (const char*)(xtb + (size_t)b * HW_ * 64);
    const float* omr = om + ((size_t)(b * H_ + y)) * 28 * 128;

    const int n15 = lane & 15;
    const int q4 = lane >> 4;
    const int px = h * 64 + wv * 16 + n15;

    f32x4 acc[4];
#pragma unroll
    for (int mt = 0; mt < 4; ++mt) acc[mt] = (f32x4){0.f, 0.f, 0.f, 0.f};

    for (int k = 0; k < 9; ++k) {
        const int ky = k / 3 - 1, kx = k % 3 - 1;

        // ---- per-lane offsets + weights for own px, all 4 corners ----
        const float dy  = omr[k * 128 + px];
        const float dxv = omr[(9 + k) * 128 + px];
        const float m   = omr[(18 + k) * 128 + px];
        const float py  = (float)(y + ky) + dy;
        const float pxe = (float)(px + kx) + dxv;
        const float y0f = floorf(py), x0f = floorf(pxe);
        const int y0i = (int)y0f, x0i = (int)x0f;
        const float wy1 = py - y0f, wx1 = pxe - x0f;
        const float wy0 = 1.f - wy1, wx0 = 1.f - wx1;

        int   offs[4];
        float wts[4];
#pragma unroll
        for (int c = 0; c < 4; ++c) {
            const int cy = c >> 1, cx = c & 1;
            const int yy = y0i + cy;
            const int xx = x0i + cx;
            const bool ok = (yy >= 0) && (yy < H_) && (xx >= 0) && (xx < W_);
            const int yc = min(max(yy, 0), H_ - 1);
            const int xc = min(max(xx, 0), W_ - 1);
            // byte offset of this lane's 8-ch group (kc=0); kc=1 adds 64 B
            offs[c] = (yc * W_ + xc) * 128 + q4 * 16;
            wts[c] = ok ? (cy ? wy1 : wy0) * (cx ? wx1 : wx0) * m : 0.f;
        }

        // ---- issue all 8 gathers up front (MLP) ----
        const u32x4 g00 = *(const u32x4*)(xbB + offs[0]);
        const u32x4 g01 = *(const u32x4*)(xbB + offs[1]);
        const u32x4 g02 = *(const u32x4*)(xbB + offs[2]);
        const u32x4 g03 = *(const u32x4*)(xbB + offs[3]);
        const u32x4 g10 = *(const u32x4*)(xbB + offs[0] + 64);
        const u32x4 g11 = *(const u32x4*)(xbB + offs[1] + 64);
        const u32x4 g12 = *(const u32x4*)(xbB + offs[2] + 64);
        const u32x4 g13 = *(const u32x4*)(xbB + offs[3] + 64);

        const float w0 = wts[0], w1 = wts[1], w2 = wts[2], w3 = wts[3];

#pragma unroll
        for (int kc = 0; kc < 2; ++kc) {
            const u32x4 c0 = kc ? g10 : g00;
            const u32x4 c1 = kc ? g11 : g01;
            const u32x4 c2 = kc ? g12 : g02;
            const u32x4 c3 = kc ? g13 : g03;
            unsigned int outw[4];
#pragma unroll
            for (int d = 0; d < 4; ++d) {
                const float lo = __uint_as_float(c0[d] << 16) * w0
                               + __uint_as_float(c1[d] << 16) * w1
                               + __uint_as_float(c2[d] << 16) * w2
                               + __uint_as_float(c3[d] << 16) * w3;
                const float hi = __uint_as_float(c0[d] & 0xffff0000u) * w0
                               + __uint_as_float(c1[d] & 0xffff0000u) * w1
                               + __uint_as_float(c2[d] & 0xffff0000u) * w2
                               + __uint_as_float(c3[d] & 0xffff0000u) * w3;
                outw[d] = cvt_pk_bf16(lo, hi);
            }
            const bf16x8 bfB = *(const bf16x8*)outw;
#pragma unroll
            for (int mt = 0; mt < 4; ++mt) {
                const bf16x8 a = *(const bf16x8*)(wrP +
                    ((((size_t)((k * 2 + kc) * 4 + mt)) * 64 + lane) * 8));
                acc[mt] = __builtin_amdgcn_mfma_f32_16x16x32_bf16(a, bfB, acc[mt], 0, 0, 0);
            }
        }
    }

    // epilogue: D[o = mt*16 + q4*4 + r][px = h*64 + wv*16 + n15], out NCHW
#pragma unroll
    for (int mt = 0; mt < 4; ++mt)
#pragma unroll
        for (int r = 0; r < 4; ++r) {
            const int o = mt * 16 + q4 * 4 + r;
            out[(((size_t)(b * 64 + o)) * H_ + y) * W_ + px] = acc[mt][r];
        }
}

// ---------------------------------------------------------------------------
extern "C" void kernel_launch(void* const* d_in, const int* in_sizes, int n_in,
                              void* d_out, int out_size, void* d_ws, size_t ws_size,
                              hipStream_t stream) {
    const float* x_img  = (const float*)d_in[0];
    const float* x_cont = (const float*)d_in[1];
    const float* w_fuse = (const float*)d_in[2];
    const float* w_off  = (const float*)d_in[3];
    const float* b_off  = (const float*)d_in[4];
    const float* w_mod  = (const float*)d_in[5];
    const float* b_mod  = (const float*)d_in[6];
    const float* w_reg  = (const float*)d_in[7];
    float* out = (float*)d_out;

    float* ws  = (float*)d_ws;
    unsigned short* wrP  = (unsigned short*)(ws + WS_WRP);
    unsigned short* wrP2 = (unsigned short*)(ws + WS_WRP2);
    unsigned short* xtb  = (unsigned short*)(ws + WS_XT);
    float* om  = ws + WS_OM;

    k_fuse<<<B_ * H_ * 2, 256, 0, stream>>>(x_img, x_cont, w_fuse, w_reg, w_off,
                                            w_mod, xtb, wrP, wrP2);
    k_offmod<<<B_ * H_ * 2, 256, 0, stream>>>(xtb, wrP2, b_off, b_mod, om);
    k_deform<<<B_ * H_ * 2, 256, 0, stream>>>(xtb, om, wrP, out);
}

// Round 2
// 222.340 us; speedup vs baseline: 1.0024x; 1.0024x over previous
//
#include <hip/hip_runtime.h>
#include <math.h>

// Problem constants
#define B_   8
#define C_   64
#define H_   128
#define W_   128
#define HW_  16384
#define K2_  9

typedef float f32x4 __attribute__((ext_vector_type(4)));
typedef short bf16x8 __attribute__((ext_vector_type(8)));
typedef unsigned short u16x4 __attribute__((ext_vector_type(4)));
typedef unsigned int u32x4 __attribute__((ext_vector_type(4)));

// Workspace layout (float offsets):
//   wrP  deform A-frags bf16    @ 8192     (36864 us)
//   wrP2 offmod A-frags bf16    @ 26624    (18432 us)
//   xt   [B][H][W][64] bf16     @ 45056    (2097152 us)
//   om   [B][y][c 0..27][px]    @ 8433664  (3670016 f)  c: 0-8 dy, 9-17 dx, 18-26 mod
#define WS_WRP  8192
#define WS_WRP2 26624
#define WS_XT   45056
#define WS_OM   8433664

static __device__ __forceinline__ unsigned short f2bf(float x) {
    unsigned int u = __float_as_uint(x);
    unsigned int r = (u + 0x7fffu + ((u >> 16) & 1u)) >> 16;   // RNE
    return (unsigned short)r;
}
static __device__ __forceinline__ float bf2f(unsigned short u) {
    return __uint_as_float(((unsigned int)u) << 16);
}
// packed f32x2 -> bf16x2 (RNE), single instruction on gfx950
static __device__ __forceinline__ unsigned int cvt_pk_bf16(float lo, float hi) {
    unsigned int r;
    asm("v_cvt_pk_bf16_f32 %0, %1, %2" : "=v"(r) : "v"(lo), "v"(hi));
    return r;
}

// ---------------------------------------------------------------------------
// Kernel 1: 1x1 fuse conv as bf16 MFMA GEMM (LDS A-frag build, direct B loads)
// + weight packing for later kernels folded into blocks 0..17.
// ---------------------------------------------------------------------------
__global__ __launch_bounds__(256) void k_fuse(const float* __restrict__ xi,
                                              const float* __restrict__ xc,
                                              const float* __restrict__ wf,
                                              const float* __restrict__ wreg,
                                              const float* __restrict__ wOff,
                                              const float* __restrict__ wMod,
                                              unsigned short* __restrict__ xtb,
                                              unsigned short* __restrict__ wrP,
                                              unsigned short* __restrict__ wrP2) {
    __shared__ unsigned short sA[1024 * 8];   // 16 KB: [f=kc*4+mt][lane][8]
    const int t = threadIdx.x;
    const int lane = t & 63;
    const int wv = t >> 6;
    const int b = blockIdx.x & 7;
    const int yh = blockIdx.x >> 3;
    const int y = yh >> 1;
    const int h = yh & 1;

    // ---- pack wrP / wrP2 (blocks 0..17 only; consumed by later kernels) ----
    if (blockIdx.x < 18) {
        const int idx = blockIdx.x * 256 + t;
        if (idx < 4608) {
            int ln = idx & 63, mt = (idx >> 6) & 3, kc = (idx >> 8) & 1, tap = idx >> 9;
            int o = mt * 16 + (ln & 15);
            int ibase = kc * 32 + (ln >> 4) * 8;
#pragma unroll
            for (int j = 0; j < 8; ++j)
                wrP[idx * 8 + j] = f2bf(wreg[(o * 64 + ibase + j) * 9 + tap]);
        }
        if (idx < 2304) {
            int ln = idx & 63, mt = (idx >> 6) & 1, kc = idx >> 7;
            int m = mt * 16 + (ln & 15);
            int gkb = kc * 32 + (ln >> 4) * 8;
#pragma unroll
            for (int j = 0; j < 8; ++j) {
                int gk = gkb + j, tap = gk >> 6, ci = gk & 63;
                float v = 0.f;
                if (m < 18)      v = wOff[(m * 64 + ci) * 9 + tap];
                else if (m < 27) v = wMod[((m - 18) * 64 + ci) * 9 + tap];
                wrP2[idx * 8 + j] = f2bf(v);
            }
        }
    }

    // ---- build fuse A-frags in LDS (each block; 32 f2bf8-chunks /thread/4) --
#pragma unroll
    for (int r = 0; r < 4; ++r) {
        const int c = t + 256 * r;      // chunk 0..1023
        const int f = c >> 6;           // f = kc*4 + mt
        const int ln = c & 63;
        const int mt = f & 3, kc = f >> 2;
        const int m = mt * 16 + (ln & 15);
        const int kb = kc * 32 + (ln >> 4) * 8;
        const float* s = wf + m * 128 + kb;
        unsigned short us[8];
#pragma unroll
        for (int j = 0; j < 8; ++j) us[j] = f2bf(s[j]);
        *(bf16x8*)&sA[c * 8] = *(const bf16x8*)us;
    }
    __syncthreads();

    const int n15 = lane & 15;
    const int q4 = lane >> 4;
    const int px = h * 64 + wv * 16 + n15;
    const size_t poff = (size_t)y * W_ + px;

    f32x4 acc[4];
#pragma unroll
    for (int mt = 0; mt < 4; ++mt) acc[mt] = (f32x4){0.f, 0.f, 0.f, 0.f};

#pragma unroll
    for (int kc = 0; kc < 4; ++kc) {
        const float* src = (kc < 2)
            ? (xi + ((size_t)(b * 64 + kc * 32 + q4 * 8)) * HW_ + poff)
            : (xc + ((size_t)(b * 64 + (kc - 2) * 32 + q4 * 8)) * HW_ + poff);
        unsigned short us[8];
#pragma unroll
        for (int j = 0; j < 8; ++j) us[j] = f2bf(src[(size_t)j * HW_]);
        const bf16x8 bf = *(const bf16x8*)us;
#pragma unroll
        for (int mt = 0; mt < 4; ++mt) {
            const bf16x8 a = *(const bf16x8*)&sA[((kc * 4 + mt) * 64 + lane) * 8];
            acc[mt] = __builtin_amdgcn_mfma_f32_16x16x32_bf16(a, bf, acc[mt], 0, 0, 0);
        }
    }

#pragma unroll
    for (int mt = 0; mt < 4; ++mt) {
        u16x4 o4;
        o4.x = f2bf(acc[mt][0]); o4.y = f2bf(acc[mt][1]);
        o4.z = f2bf(acc[mt][2]); o4.w = f2bf(acc[mt][3]);
        *(u16x4*)&xtb[((size_t)b * HW_ + poff) * 64 + mt * 16 + q4 * 4] = o4;
    }
}

// ---------------------------------------------------------------------------
// Kernel 2: 3x3 off+mod convs as im2col bf16 MFMA GEMM. om layout [c][px].
// ---------------------------------------------------------------------------
__global__ __launch_bounds__(256) void k_offmod(const unsigned short* __restrict__ xtb,
                                                const unsigned short* __restrict__ wrP2,
                                                const float* __restrict__ bOff,
                                                const float* __restrict__ bMod,
                                                float* __restrict__ om) {
    __shared__ unsigned short sB[3 * 66 * 72];   // 28512 B
    const int t = threadIdx.x;
    const int lane = t & 63;
    const int wv = t >> 6;
    const int b = blockIdx.x & 7;
    const int yh = blockIdx.x >> 3;
    const int y = yh >> 1;
    const int h = yh & 1;

    for (int idx = t; idx < 3 * 66 * 8; idx += 256) {
        const int c8 = idx & 7;
        const int pp = (idx >> 3) % 66;
        const int row = (idx >> 3) / 66;
        const int gx = h * 64 + pp - 1;
        const int gy = y + row - 1;
        bf16x8 v = {0, 0, 0, 0, 0, 0, 0, 0};
        if (gx >= 0 && gx < W_ && gy >= 0 && gy < H_)
            v = *(const bf16x8*)&xtb[(((size_t)(b * H_ + gy)) * W_ + gx) * 64 + c8 * 8];
        *(bf16x8*)&sB[(row * 66 + pp) * 72 + c8 * 8] = v;
    }
    __syncthreads();

    const int n15 = lane & 15;
    const int q4 = lane >> 4;

    f32x4 acc[2];
    acc[0] = (f32x4){0.f, 0.f, 0.f, 0.f};
    acc[1] = (f32x4){0.f, 0.f, 0.f, 0.f};

#pragma unroll
    for (int kc = 0; kc < 18; ++kc) {
        const int gkb = kc * 32 + q4 * 8;
        const int tap = gkb >> 6;
        const int ci = gkb & 63;
        const int row = tap / 3, kx = tap % 3;
        const bf16x8 bf = *(const bf16x8*)&sB[(row * 66 + (wv * 16 + n15 + kx)) * 72 + ci];
        const bf16x8 a0 = *(const bf16x8*)(wrP2 + (((size_t)(kc * 2 + 0) * 64 + lane) * 8));
        const bf16x8 a1 = *(const bf16x8*)(wrP2 + (((size_t)(kc * 2 + 1) * 64 + lane) * 8));
        acc[0] = __builtin_amdgcn_mfma_f32_16x16x32_bf16(a0, bf, acc[0], 0, 0, 0);
        acc[1] = __builtin_amdgcn_mfma_f32_16x16x32_bf16(a1, bf, acc[1], 0, 0, 0);
    }

    const int px = h * 64 + wv * 16 + n15;
    const size_t rec = ((size_t)(b * H_ + y)) * 28 * 128;
#pragma unroll
    for (int mt = 0; mt < 2; ++mt)
#pragma unroll
        for (int r = 0; r < 4; ++r) {
            const int o = mt * 16 + q4 * 4 + r;
            if (o < 18) {
                const int c = (o >> 1) + ((o & 1) ? 9 : 0);
                om[rec + c * 128 + px] = acc[mt][r] + bOff[o];
            } else if (o < 27) {
                const float z = acc[mt][r] + bMod[o - 18];
                om[rec + (18 + (o - 18)) * 128 + px] = 2.f / (1.f + __expf(-z));
            }
        }
}

// ---------------------------------------------------------------------------
// Kernel 3: deformable sampling + modulation + bf16 MFMA einsum.
// grid = B*H*2 = 2048, 4 waves x 16 px. ZERO LDS, ZERO barriers.
// Latency-hiding v3: all 27 om values hoisted to registers at entry;
// 2-deep software pipeline over taps — STAGE(k+1) issues its 8 gathers
// (alternate register buffer) BEFORE BLEND(k) consumes tap k's, so each
// tap's scattered-L2 gather latency (~200-400 cyc) hides under the previous
// tap's blend VALU + A-frag loads + 8 MFMAs. Fully unrolled: all buffer
// indices compile-time (no scratch).
// ---------------------------------------------------------------------------

// compute offsets/weights for tap K and issue its 8 gathers into slot S
#define STAGE(K, S) do {                                                      \
    const float dy_  = omv[(K)];                                              \
    const float dxv_ = omv[9 + (K)];                                          \
    const float m_   = omv[18 + (K)];                                         \
    const float py_  = (float)(y + ((K) / 3 - 1)) + dy_;                      \
    const float pxe_ = (float)(px + ((K) % 3 - 1)) + dxv_;                    \
    const float y0f_ = floorf(py_), x0f_ = floorf(pxe_);                      \
    const int y0i_ = (int)y0f_, x0i_ = (int)x0f_;                             \
    const float wy1_ = py_ - y0f_, wx1_ = pxe_ - x0f_;                        \
    const float wy0_ = 1.f - wy1_, wx0_ = 1.f - wx1_;                         \
    _Pragma("unroll")                                                         \
    for (int c_ = 0; c_ < 4; ++c_) {                                          \
        const int cy_ = c_ >> 1, cx_ = c_ & 1;                                \
        const int yy_ = y0i_ + cy_;                                           \
        const int xx_ = x0i_ + cx_;                                           \
        const bool ok_ = (yy_ >= 0) && (yy_ < H_) && (xx_ >= 0) && (xx_ < W_);\
        const int yc_ = min(max(yy_, 0), H_ - 1);                             \
        const int xc_ = min(max(xx_, 0), W_ - 1);                             \
        const int off_ = (yc_ * W_ + xc_) * 128 + q4 * 16;                    \
        wts[S][c_] = ok_ ? (cy_ ? wy1_ : wy0_) * (cx_ ? wx1_ : wx0_) * m_     \
                         : 0.f;                                               \
        g[S][c_]     = *(const u32x4*)(xbB + off_);                           \
        g[S][4 + c_] = *(const u32x4*)(xbB + off_ + 64);                      \
    }                                                                         \
} while (0)

// blend tap K's 4 corners (slot S), pack to bf16 B-frag, run 8 MFMAs
#define BLEND(K, S) do {                                                      \
    const float w0_ = wts[S][0], w1_ = wts[S][1];                             \
    const float w2_ = wts[S][2], w3_ = wts[S][3];                             \
    _Pragma("unroll")                                                         \
    for (int kc_ = 0; kc_ < 2; ++kc_) {                                       \
        unsigned int outw_[4];                                                \
        _Pragma("unroll")                                                     \
        for (int d_ = 0; d_ < 4; ++d_) {                                      \
            const unsigned int a_ = g[S][kc_ * 4 + 0][d_];                    \
            const unsigned int b_ = g[S][kc_ * 4 + 1][d_];                    \
            const unsigned int c_ = g[S][kc_ * 4 + 2][d_];                    \
            const unsigned int e_ = g[S][kc_ * 4 + 3][d_];                    \
            const float lo_ = __uint_as_float(a_ << 16) * w0_                 \
                            + __uint_as_float(b_ << 16) * w1_                 \
                            + __uint_as_float(c_ << 16) * w2_                 \
                            + __uint_as_float(e_ << 16) * w3_;                \
            const float hi_ = __uint_as_float(a_ & 0xffff0000u) * w0_         \
                            + __uint_as_float(b_ & 0xffff0000u) * w1_         \
                            + __uint_as_float(c_ & 0xffff0000u) * w2_         \
                            + __uint_as_float(e_ & 0xffff0000u) * w3_;        \
            outw_[d_] = cvt_pk_bf16(lo_, hi_);                                \
        }                                                                     \
        const bf16x8 bfB_ = *(const bf16x8*)outw_;                            \
        _Pragma("unroll")                                                     \
        for (int mt_ = 0; mt_ < 4; ++mt_) {                                   \
            const bf16x8 a2_ = *(const bf16x8*)(wrP +                         \
                ((((size_t)(((K) * 2 + kc_) * 4 + mt_)) * 64 + lane) * 8));   \
            acc[mt_] = __builtin_amdgcn_mfma_f32_16x16x32_bf16(a2_, bfB_,     \
                                                               acc[mt_],     \
                                                               0, 0, 0);      \
        }                                                                     \
    }                                                                         \
} while (0)

__global__ __launch_bounds__(256) void k_deform(const unsigned short* __restrict__ xtb,
                                                const float* __restrict__ om,
                                                const unsigned short* __restrict__ wrP,
                                                float* __restrict__ out) {
    const int t = threadIdx.x;
    const int lane = t & 63;
    const int wv = t >> 6;
    const int b = blockIdx.x & 7;
    const int yh = blockIdx.x >> 3;
    const int y = yh >> 1;
    const int h = yh & 1;

    const char* xbB = (const char*)(xtb + (size_t)b * HW_ * 64);
    const float* omr = om + ((size_t)(b * H_ + y)) * 28 * 128;

    const int n15 = lane & 15;
    const int q4 = lane >> 4;
    const int px = h * 64 + wv * 16 + n15;

    // ---- hoist all 27 om values (coalesced, fixed addresses) ----
    float omv[27];
#pragma unroll
    for (int i = 0; i < 27; ++i) omv[i] = omr[i * 128 + px];

    f32x4 acc[4];
#pragma unroll
    for (int mt = 0; mt < 4; ++mt) acc[mt] = (f32x4){0.f, 0.f, 0.f, 0.f};

    u32x4 g[2][8];
    float wts[2][4];

    // ---- 2-deep pipelined tap loop (fully unrolled; all indices static) ----
    STAGE(0, 0);
#pragma unroll
    for (int k = 0; k < 9; ++k) {
        if (k < 8) {
            if ((k & 1) == 0) STAGE(k + 1, 1);
            else              STAGE(k + 1, 0);
        }
        if ((k & 1) == 0) BLEND(k, 0);
        else              BLEND(k, 1);
    }

    // epilogue: D[o = mt*16 + q4*4 + r][px = h*64 + wv*16 + n15], out NCHW
#pragma unroll
    for (int mt = 0; mt < 4; ++mt)
#pragma unroll
        for (int r = 0; r < 4; ++r) {
            const int o = mt * 16 + q4 * 4 + r;
            out[(((size_t)(b * 64 + o)) * H_ + y) * W_ + px] = acc[mt][r];
        }
}

// ---------------------------------------------------------------------------
extern "C" void kernel_launch(void* const* d_in, const int* in_sizes, int n_in,
                              void* d_out, int out_size, void* d_ws, size_t ws_size,
                              hipStream_t stream) {
    const float* x_img  = (const float*)d_in[0];
    const float* x_cont = (const float*)d_in[1];
    const float* w_fuse = (const float*)d_in[2];
    const float* w_off  = (const float*)d_in[3];
    const float* b_off  = (const float*)d_in[4];
    const float* w_mod  = (const float*)d_in[5];
    const float* b_mod  = (const float*)d_in[6];
    const float* w_reg  = (const float*)d_in[7];
    float* out = (float*)d_out;

    float* ws  = (float*)d_ws;
    unsigned short* wrP  = (unsigned short*)(ws + WS_WRP);
    unsigned short* wrP2 = (unsigned short*)(ws + WS_WRP2);
    unsigned short* xtb  = (unsigned short*)(ws + WS_XT);
    float* om  = ws + WS_OM;

    k_fuse<<<B_ * H_ * 2, 256, 0, stream>>>(x_img, x_cont, w_fuse, w_reg, w_off,
                                            w_mod, xtb, wrP, wrP2);
    k_offmod<<<B_ * H_ * 2, 256, 0, stream>>>(xtb, wrP2, b_off, b_mod, om);
    k_deform<<<B_ * H_ * 2, 256, 0, stream>>>(xtb, om, wrP, out);
}

// Round 7
// 194.544 us; speedup vs baseline: 1.1456x; 1.1429x over previous
//
#include <hip/hip_runtime.h>
#include <math.h>

// Problem constants
#define B_   8
#define C_   64
#define H_   128
#define W_   128
#define HW_  16384
#define K2_  9

typedef float f32x4 __attribute__((ext_vector_type(4)));
typedef short bf16x8 __attribute__((ext_vector_type(8)));
typedef unsigned short u16x4 __attribute__((ext_vector_type(4)));
typedef unsigned int u32x4 __attribute__((ext_vector_type(4)));

// Workspace layout (float offsets):
//   wrP  deform A-frags bf16    @ 8192     (36864 us)
//   wrP2 offmod A-frags bf16    @ 26624    (18432 us)
//   xt   [B][H][W][64] bf16     @ 45056    (2097152 us)
//   om   [B][y][c 0..27][px]    @ 8433664  (3670016 f)  c: 0-8 dy, 9-17 dx, 18-26 mod
#define WS_WRP  8192
#define WS_WRP2 26624
#define WS_XT   45056
#define WS_OM   8433664

static __device__ __forceinline__ unsigned short f2bf(float x) {
    unsigned int u = __float_as_uint(x);
    unsigned int r = (u + 0x7fffu + ((u >> 16) & 1u)) >> 16;   // RNE
    return (unsigned short)r;
}
static __device__ __forceinline__ float bf2f(unsigned short u) {
    return __uint_as_float(((unsigned int)u) << 16);
}
// packed f32x2 -> bf16x2 (RNE), single instruction on gfx950
static __device__ __forceinline__ unsigned int cvt_pk_bf16(float lo, float hi) {
    unsigned int r;
    asm("v_cvt_pk_bf16_f32 %0, %1, %2" : "=v"(r) : "v"(lo), "v"(hi));
    return r;
}
// element-wise register select (compiles to v_cndmask; no control flow)
static __device__ __forceinline__ u32x4 sel4(bool c, u32x4 a, u32x4 b) {
    u32x4 r;
    r[0] = c ? a[0] : b[0];
    r[1] = c ? a[1] : b[1];
    r[2] = c ? a[2] : b[2];
    r[3] = c ? a[3] : b[3];
    return r;
}

// ---------------------------------------------------------------------------
// Kernel 1: 1x1 fuse conv as bf16 MFMA GEMM (byte-identical to passing r2)
// ---------------------------------------------------------------------------
__global__ __launch_bounds__(256) void k_fuse(const float* __restrict__ xi,
                                              const float* __restrict__ xc,
                                              const float* __restrict__ wf,
                                              const float* __restrict__ wreg,
                                              const float* __restrict__ wOff,
                                              const float* __restrict__ wMod,
                                              unsigned short* __restrict__ xtb,
                                              unsigned short* __restrict__ wrP,
                                              unsigned short* __restrict__ wrP2) {
    __shared__ unsigned short sA[1024 * 8];   // 16 KB: [f=kc*4+mt][lane][8]
    const int t = threadIdx.x;
    const int lane = t & 63;
    const int wv = t >> 6;
    const int b = blockIdx.x & 7;
    const int yh = blockIdx.x >> 3;
    const int y = yh >> 1;
    const int h = yh & 1;

    // ---- pack wrP / wrP2 (blocks 0..17 only; consumed by later kernels) ----
    if (blockIdx.x < 18) {
        const int idx = blockIdx.x * 256 + t;
        if (idx < 4608) {
            int ln = idx & 63, mt = (idx >> 6) & 3, kc = (idx >> 8) & 1, tap = idx >> 9;
            int o = mt * 16 + (ln & 15);
            int ibase = kc * 32 + (ln >> 4) * 8;
#pragma unroll
            for (int j = 0; j < 8; ++j)
                wrP[idx * 8 + j] = f2bf(wreg[(o * 64 + ibase + j) * 9 + tap]);
        }
        if (idx < 2304) {
            int ln = idx & 63, mt = (idx >> 6) & 1, kc = idx >> 7;
            int m = mt * 16 + (ln & 15);
            int gkb = kc * 32 + (ln >> 4) * 8;
#pragma unroll
            for (int j = 0; j < 8; ++j) {
                int gk = gkb + j, tap = gk >> 6, ci = gk & 63;
                float v = 0.f;
                if (m < 18)      v = wOff[(m * 64 + ci) * 9 + tap];
                else if (m < 27) v = wMod[((m - 18) * 64 + ci) * 9 + tap];
                wrP2[idx * 8 + j] = f2bf(v);
            }
        }
    }

    // ---- build fuse A-frags in LDS (each block; 32 f2bf8-chunks /thread/4) --
#pragma unroll
    for (int r = 0; r < 4; ++r) {
        const int c = t + 256 * r;      // chunk 0..1023
        const int f = c >> 6;           // f = kc*4 + mt
        const int ln = c & 63;
        const int mt = f & 3, kc = f >> 2;
        const int m = mt * 16 + (ln & 15);
        const int kb = kc * 32 + (ln >> 4) * 8;
        const float* s = wf + m * 128 + kb;
        unsigned short us[8];
#pragma unroll
        for (int j = 0; j < 8; ++j) us[j] = f2bf(s[j]);
        *(bf16x8*)&sA[c * 8] = *(const bf16x8*)us;
    }
    __syncthreads();

    const int n15 = lane & 15;
    const int q4 = lane >> 4;
    const int px = h * 64 + wv * 16 + n15;
    const size_t poff = (size_t)y * W_ + px;

    f32x4 acc[4];
#pragma unroll
    for (int mt = 0; mt < 4; ++mt) acc[mt] = (f32x4){0.f, 0.f, 0.f, 0.f};

#pragma unroll
    for (int kc = 0; kc < 4; ++kc) {
        const float* src = (kc < 2)
            ? (xi + ((size_t)(b * 64 + kc * 32 + q4 * 8)) * HW_ + poff)
            : (xc + ((size_t)(b * 64 + (kc - 2) * 32 + q4 * 8)) * HW_ + poff);
        unsigned short us[8];
#pragma unroll
        for (int j = 0; j < 8; ++j) us[j] = f2bf(src[(size_t)j * HW_]);
        const bf16x8 bf = *(const bf16x8*)us;
#pragma unroll
        for (int mt = 0; mt < 4; ++mt) {
            const bf16x8 a = *(const bf16x8*)&sA[((kc * 4 + mt) * 64 + lane) * 8];
            acc[mt] = __builtin_amdgcn_mfma_f32_16x16x32_bf16(a, bf, acc[mt], 0, 0, 0);
        }
    }

#pragma unroll
    for (int mt = 0; mt < 4; ++mt) {
        u16x4 o4;
        o4.x = f2bf(acc[mt][0]); o4.y = f2bf(acc[mt][1]);
        o4.z = f2bf(acc[mt][2]); o4.w = f2bf(acc[mt][3]);
        *(u16x4*)&xtb[((size_t)b * HW_ + poff) * 64 + mt * 16 + q4 * 4] = o4;
    }
}

// ---------------------------------------------------------------------------
// Kernel 2: 3x3 off+mod convs (byte-identical to passing r2). om global.
// ---------------------------------------------------------------------------
__global__ __launch_bounds__(256) void k_offmod(const unsigned short* __restrict__ xtb,
                                                const unsigned short* __restrict__ wrP2,
                                                const float* __restrict__ bOff,
                                                const float* __restrict__ bMod,
                                                float* __restrict__ om) {
    __shared__ unsigned short sB[3 * 66 * 72];   // 28512 B
    const int t = threadIdx.x;
    const int lane = t & 63;
    const int wv = t >> 6;
    const int b = blockIdx.x & 7;
    const int yh = blockIdx.x >> 3;
    const int y = yh >> 1;
    const int h = yh & 1;

    for (int idx = t; idx < 3 * 66 * 8; idx += 256) {
        const int c8 = idx & 7;
        const int pp = (idx >> 3) % 66;
        const int row = (idx >> 3) / 66;
        const int gx = h * 64 + pp - 1;
        const int gy = y + row - 1;
        bf16x8 v = {0, 0, 0, 0, 0, 0, 0, 0};
        if (gx >= 0 && gx < W_ && gy >= 0 && gy < H_)
            v = *(const bf16x8*)&xtb[(((size_t)(b * H_ + gy)) * W_ + gx) * 64 + c8 * 8];
        *(bf16x8*)&sB[(row * 66 + pp) * 72 + c8 * 8] = v;
    }
    __syncthreads();

    const int n15 = lane & 15;
    const int q4 = lane >> 4;

    f32x4 acc[2];
    acc[0] = (f32x4){0.f, 0.f, 0.f, 0.f};
    acc[1] = (f32x4){0.f, 0.f, 0.f, 0.f};

#pragma unroll
    for (int kc = 0; kc < 18; ++kc) {
        const int gkb = kc * 32 + q4 * 8;
        const int tap = gkb >> 6;
        const int ci = gkb & 63;
        const int row = tap / 3, kx = tap % 3;
        const bf16x8 bf = *(const bf16x8*)&sB[(row * 66 + (wv * 16 + n15 + kx)) * 72 + ci];
        const bf16x8 a0 = *(const bf16x8*)(wrP2 + (((size_t)(kc * 2 + 0) * 64 + lane) * 8));
        const bf16x8 a1 = *(const bf16x8*)(wrP2 + (((size_t)(kc * 2 + 1) * 64 + lane) * 8));
        acc[0] = __builtin_amdgcn_mfma_f32_16x16x32_bf16(a0, bf, acc[0], 0, 0, 0);
        acc[1] = __builtin_amdgcn_mfma_f32_16x16x32_bf16(a1, bf, acc[1], 0, 0, 0);
    }

    const int px = h * 64 + wv * 16 + n15;
    const size_t rec = ((size_t)(b * H_ + y)) * 28 * 128;
#pragma unroll
    for (int mt = 0; mt < 2; ++mt)
#pragma unroll
        for (int r = 0; r < 4; ++r) {
            const int o = mt * 16 + q4 * 4 + r;
            if (o < 18) {
                const int c = (o >> 1) + ((o & 1) ? 9 : 0);
                om[rec + c * 128 + px] = acc[mt][r] + bOff[o];
            } else if (o < 27) {
                const float z = acc[mt][r] + bMod[o - 18];
                om[rec + (18 + (o - 18)) * 128 + px] = 2.f / (1.f + __expf(-z));
            }
        }
}

// ---------------------------------------------------------------------------
// Kernel 3: deformable sampling + MFMA einsum.  Window gather rebuilt from
// proven constructs only:
//   - LDS read typed bf16x8 (same type as the store — every passing kernel's
//     pattern), at an unconditionally CLAMPED window address (always valid,
//     no ternary address, no OOB).
//   - Global load ALWAYS issued at a clamped valid address (r1's proven
//     pattern); for in-window lanes the address folds to record 0, a single
//     L1-hot broadcast line, so scattered-L2 traffic still collapses.
//   - Per-element register select (cndmask) LDS vs global — zero divergent
//     control flow, no conditional writes into vector arrays.
// ---------------------------------------------------------------------------
__global__ __launch_bounds__(256) void k_deform(const unsigned short* __restrict__ xtb,
                                                const float* __restrict__ om,
                                                const unsigned short* __restrict__ wrP,
                                                float* __restrict__ out) {
    __shared__ __align__(16) unsigned short sW[5 * 68 * 72];  // 48960 B
    const int t = threadIdx.x;
    const int lane = t & 63;
    const int wv = t >> 6;
    const int b = blockIdx.x & 7;
    const int yh = blockIdx.x >> 3;
    const int y = yh >> 1;
    const int h = yh & 1;
    const int wx0 = h * 64 - 2;   // window px origin
    const int ylo = y - 2;        // window row origin

    // ---- stage 5x68 window (coalesced global reads, aligned b128 writes) --
    for (int i = t; i < 2720; i += 256) {
        const int c8 = i & 7;
        const int p  = (i >> 3) % 68;
        const int r  = (i >> 3) / 68;
        const int gx = wx0 + p;
        const int gy = ylo + r;
        bf16x8 v = {0, 0, 0, 0, 0, 0, 0, 0};
        if (gx >= 0 && gx < W_ && gy >= 0 && gy < H_)
            v = *(const bf16x8*)&xtb[(((size_t)(b * H_ + gy)) * W_ + gx) * 64 + c8 * 8];
        *(bf16x8*)&sW[(r * 68 + p) * 72 + c8 * 8] = v;
    }
    __syncthreads();

    const char* xbB = (const char*)(xtb + (size_t)b * HW_ * 64);
    const float* omr = om + ((size_t)(b * H_ + y)) * 28 * 128;

    const int n15 = lane & 15;
    const int q4 = lane >> 4;
    const int px = h * 64 + wv * 16 + n15;

    // ---- hoist all 27 om values (global, as in passing r1) ----
    float omv[27];
#pragma unroll
    for (int i = 0; i < 27; ++i) omv[i] = omr[i * 128 + px];

    f32x4 acc[4];
#pragma unroll
    for (int mt = 0; mt < 4; ++mt) acc[mt] = (f32x4){0.f, 0.f, 0.f, 0.f};

    for (int k = 0; k < 9; ++k) {
        const int ky = k / 3 - 1, kx = k % 3 - 1;
        const float dy  = omv[k];
        const float dxv = omv[9 + k];
        const float m   = omv[18 + k];
        const float py  = (float)(y + ky) + dy;
        const float pxe = (float)(px + kx) + dxv;
        const float y0f = floorf(py), x0f = floorf(pxe);
        const int y0i = (int)y0f, x0i = (int)x0f;
        const float wy1 = py - y0f, wx1 = pxe - x0f;
        const float wy0 = 1.f - wy1, wx0f = 1.f - wx1;

        u32x4 gv[8];
        float wts[4];
#pragma unroll
        for (int c = 0; c < 4; ++c) {
            const int cy = c >> 1, cx = c & 1;
            const int yy = y0i + cy;
            const int xx = x0i + cx;
            const bool ok = (yy >= 0) && (yy < H_) && (xx >= 0) && (xx < W_);
            wts[c] = ok ? (cy ? wy1 : wy0) * (cx ? wx1 : wx0f) * m : 0.f;
            const bool inw = (yy >= ylo) && (yy <= ylo + 4)
                          && (xx >= wx0) && (xx < wx0 + 68);
            // clamped window coords: LDS address always valid & staged
            int wr = yy - ylo; wr = min(max(wr, 0), 4);
            int wc = xx - wx0; wc = min(max(wc, 0), 67);
            const int lsW = (wr * 68 + wc) * 72 + q4 * 8;
            const bf16x8 l0 = *(const bf16x8*)&sW[lsW];
            const bf16x8 l1 = *(const bf16x8*)&sW[lsW + 32];
            // clamped global address; in-window lanes fold to record 0 (L1-hot)
            const int yc = min(max(yy, 0), H_ - 1);
            const int xc = min(max(xx, 0), W_ - 1);
            const int off = inw ? (q4 * 16) : ((yc * W_ + xc) * 128 + q4 * 16);
            const bf16x8 g0 = *(const bf16x8*)(xbB + off);
            const bf16x8 g1 = *(const bf16x8*)(xbB + off + 64);
            u32x4 lu0, lu1, gu0, gu1;
            __builtin_memcpy(&lu0, &l0, 16);
            __builtin_memcpy(&lu1, &l1, 16);
            __builtin_memcpy(&gu0, &g0, 16);
            __builtin_memcpy(&gu1, &g1, 16);
            gv[c]     = sel4(inw, lu0, gu0);
            gv[4 + c] = sel4(inw, lu1, gu1);
        }

        const float w0 = wts[0], w1 = wts[1], w2 = wts[2], w3 = wts[3];
#pragma unroll
        for (int kc = 0; kc < 2; ++kc) {
            unsigned int outw[4];
#pragma unroll
            for (int d = 0; d < 4; ++d) {
                const unsigned int av = gv[kc * 4 + 0][d];
                const unsigned int bv = gv[kc * 4 + 1][d];
                const unsigned int cv = gv[kc * 4 + 2][d];
                const unsigned int ev = gv[kc * 4 + 3][d];
                const float lo = __uint_as_float(av << 16) * w0
                               + __uint_as_float(bv << 16) * w1
                               + __uint_as_float(cv << 16) * w2
                               + __uint_as_float(ev << 16) * w3;
                const float hi = __uint_as_float(av & 0xffff0000u) * w0
                               + __uint_as_float(bv & 0xffff0000u) * w1
                               + __uint_as_float(cv & 0xffff0000u) * w2
                               + __uint_as_float(ev & 0xffff0000u) * w3;
                outw[d] = cvt_pk_bf16(lo, hi);
            }
            const bf16x8 bfB = *(const bf16x8*)outw;
#pragma unroll
            for (int mt = 0; mt < 4; ++mt) {
                const bf16x8 a = *(const bf16x8*)(wrP +
                    ((((size_t)((k * 2 + kc) * 4 + mt)) * 64 + lane) * 8));
                acc[mt] = __builtin_amdgcn_mfma_f32_16x16x32_bf16(a, bfB, acc[mt], 0, 0, 0);
            }
        }
    }

    // epilogue: D[o = mt*16 + q4*4 + r][px], out NCHW
#pragma unroll
    for (int mt = 0; mt < 4; ++mt)
#pragma unroll
        for (int r = 0; r < 4; ++r) {
            const int o = mt * 16 + q4 * 4 + r;
            out[(((size_t)(b * 64 + o)) * H_ + y) * W_ + px] = acc[mt][r];
        }
}

// ---------------------------------------------------------------------------
extern "C" void kernel_launch(void* const* d_in, const int* in_sizes, int n_in,
                              void* d_out, int out_size, void* d_ws, size_t ws_size,
                              hipStream_t stream) {
    const float* x_img  = (const float*)d_in[0];
    const float* x_cont = (const float*)d_in[1];
    const float* w_fuse = (const float*)d_in[2];
    const float* w_off  = (const float*)d_in[3];
    const float* b_off  = (const float*)d_in[4];
    const float* w_mod  = (const float*)d_in[5];
    const float* b_mod  = (const float*)d_in[6];
    const float* w_reg  = (const float*)d_in[7];
    float* out = (float*)d_out;

    float* ws  = (float*)d_ws;
    unsigned short* wrP  = (unsigned short*)(ws + WS_WRP);
    unsigned short* wrP2 = (unsigned short*)(ws + WS_WRP2);
    unsigned short* xtb  = (unsigned short*)(ws + WS_XT);
    float* om  = ws + WS_OM;

    k_fuse<<<B_ * H_ * 2, 256, 0, stream>>>(x_img, x_cont, w_fuse, w_reg, w_off,
                                            w_mod, xtb, wrP, wrP2);
    k_offmod<<<B_ * H_ * 2, 256, 0, stream>>>(xtb, wrP2, b_off, b_mod, om);
    k_deform<<<B_ * H_ * 2, 256, 0, stream>>>(xtb, om, wrP, out);
}